// Round 1
// baseline (760.504 us; speedup 1.0000x reference)
//
#include <hip/hip_runtime.h>
#include <cstdint>
#include <cstddef>

// Problem constants (from reference): T=512, B=32, A=64, N=128, H=8
#define A_DIM 64
#define N_DIM 128
#define H_DIM 8
#define OUT_PER_BLK (A_DIM * (A_DIM - 1))   // 4032 floats
#define ATT_STRIDE 68                        // 64 + 4 pad: breaks LDS bank conflicts, keeps 16B align

// One block per (t,b). 256 threads = 4 waves.
__global__ __launch_bounds__(256, 4) void attn_kernel(
    const float* __restrict__ S,
    const float* __restrict__ Wq,
    const float* __restrict__ bq,
    const float* __restrict__ Wk,
    const float* __restrict__ bk,
    float* __restrict__ out)
{
    // smem: phase 1-2 uses it as partial[w][g][i] (4*16*64 = 4096 floats),
    //        phase 4-5 reuses it as att[i][ATT_STRIDE] (64*68 = 4352 floats)
    __shared__ float smem[A_DIM * ATT_STRIDE];
    __shared__ float q_lds[A_DIM * H_DIM];
    __shared__ float k_lds[A_DIM * H_DIM];   // flat [i*8+h] == K2[h][j] at [h*64+j]

    const int tid  = threadIdx.x;
    const int blk  = blockIdx.x;                                  // t*B + b
    const int lane = tid & 63;
    const int wv   = __builtin_amdgcn_readfirstlane(tid >> 6);    // wave id, provably uniform

    // ---------------- Phase 1: partial projections ----------------
    // wave wv handles n in [wv*32, wv*32+32) for all 64 rows (row = lane)
    const int n0 = wv * 32;
    const float* srow = S + (size_t)blk * (A_DIM * N_DIM) + (size_t)lane * N_DIM + n0;
    float sb[32];
    {
        const float4* sp = (const float4*)srow;   // 16B aligned: lane*512 + wv*128
        #pragma unroll
        for (int c = 0; c < 8; ++c) {
            float4 v = sp[c];
            sb[4*c+0] = v.x; sb[4*c+1] = v.y; sb[4*c+2] = v.z; sb[4*c+3] = v.w;
        }
    }

    float qa[H_DIM] = {0,0,0,0,0,0,0,0};
    float ka[H_DIM] = {0,0,0,0,0,0,0,0};
    #pragma unroll
    for (int j = 0; j < 32; ++j) {
        const float s = sb[j];
        const float* wqj = Wq + (n0 + j) * H_DIM;   // wave-uniform address -> s_load
        const float* wkj = Wk + (n0 + j) * H_DIM;
        #pragma unroll
        for (int h = 0; h < H_DIM; ++h) {
            qa[h] = fmaf(s, wqj[h], qa[h]);
            ka[h] = fmaf(s, wkj[h], ka[h]);
        }
    }
    // partial[w][g][i]: g 0..7 = q[h], g 8..15 = k[h]; lanes i consecutive -> conflict-free
    {
        float* p = smem + wv * (16 * 64) + lane;
        #pragma unroll
        for (int h = 0; h < H_DIM; ++h) {
            p[h * 64]       = qa[h];
            p[(8 + h) * 64] = ka[h];
        }
    }
    __syncthreads();

    // ---------------- Phase 2: reduce over waves + bias ----------------
    // thread (ii = tid>>2, h2 = tid&3) produces q[ii][h2], q[ii][h2+4], k[ii][h2], k[ii][h2+4]
    {
        const int ii = tid >> 2;
        const int h2 = tid & 3;
        float v0 = 0.f, v1 = 0.f, v2 = 0.f, v3 = 0.f;
        #pragma unroll
        for (int w = 0; w < 4; ++w) {
            const float* p = smem + w * (16 * 64) + ii;
            v0 += p[(h2     ) * 64];
            v1 += p[(h2 +  4) * 64];
            v2 += p[(h2 +  8) * 64];
            v3 += p[(h2 + 12) * 64];
        }
        q_lds[ii * 8 + h2    ] = v0 + bq[h2];
        q_lds[ii * 8 + h2 + 4] = v1 + bq[h2 + 4];
        k_lds[ii * 8 + h2    ] = v2 + bk[h2];
        k_lds[ii * 8 + h2 + 4] = v3 + bk[h2 + 4];
    }
    __syncthreads();

    // ---------------- Phase 3: att = Q @ K2 ----------------
    // thread (i = tid>>2, jb = tid&3) computes att[i][jb*16 .. jb*16+16)
    const int i  = tid >> 2;
    const int jb = tid & 3;
    float qv[H_DIM];
    #pragma unroll
    for (int h = 0; h < H_DIM; ++h) qv[h] = q_lds[i * 8 + h];

    float acc[16];
    #pragma unroll
    for (int c = 0; c < 16; ++c) acc[c] = 0.f;
    #pragma unroll
    for (int h = 0; h < H_DIM; ++h) {
        // K2[h][j] = k_flat[h*64 + j]  (the reference "reshape" for free)
        const float* kr = k_lds + h * 64 + jb * 16;
        const float qh = qv[h];
        #pragma unroll
        for (int c = 0; c < 16; ++c) acc[c] = fmaf(qh, kr[c], acc[c]);
    }

    // ---------------- Phase 4: softmax over j (4 lanes per row) ----------------
    float m = acc[0];
    #pragma unroll
    for (int c = 1; c < 16; ++c) m = fmaxf(m, acc[c]);
    m = fmaxf(m, __shfl_xor(m, 1, 64));
    m = fmaxf(m, __shfl_xor(m, 2, 64));
    float ssum = 0.f;
    #pragma unroll
    for (int c = 0; c < 16; ++c) { acc[c] = __expf(acc[c] - m); ssum += acc[c]; }
    ssum += __shfl_xor(ssum, 1, 64);
    ssum += __shfl_xor(ssum, 2, 64);
    const float inv = 1.0f / ssum;

    {
        float* ar = smem + i * ATT_STRIDE + jb * 16;
        #pragma unroll
        for (int c = 0; c < 16; ++c) ar[c] = acc[c] * inv;
    }
    __syncthreads();

    // ---------------- Phase 5: off-diagonal gather, coalesced float4 stores ----------------
    // out[blk][i][k] = att[i][k + (k>=i)], flat 4032 floats = 1008 float4 per block
    float4* out4 = (float4*)(out + (size_t)blk * OUT_PER_BLK);
    #pragma unroll
    for (int it = 0; it < 4; ++it) {
        const int o4 = it * 256 + tid;
        if (o4 < OUT_PER_BLK / 4) {
            float tmp[4];
            #pragma unroll
            for (int e = 0; e < 4; ++e) {
                const int idx = o4 * 4 + e;          // 0..4031
                const int ii  = idx / 63;            // magic-mul
                const int kk  = idx - ii * 63;
                const int jj  = kk + (kk >= ii ? 1 : 0);
                tmp[e] = smem[ii * ATT_STRIDE + jj];
            }
            out4[o4] = make_float4(tmp[0], tmp[1], tmp[2], tmp[3]);
        }
    }
}

extern "C" void kernel_launch(void* const* d_in, const int* in_sizes, int n_in,
                              void* d_out, int out_size, void* d_ws, size_t ws_size,
                              hipStream_t stream) {
    const float* S  = (const float*)d_in[0];   // (T,B,A,N) fp32
    const float* Wq = (const float*)d_in[1];   // (N,H)
    const float* bq = (const float*)d_in[2];   // (H,)
    const float* Wk = (const float*)d_in[3];   // (N,H)
    const float* bk = (const float*)d_in[4];   // (H,)
    float* out = (float*)d_out;                // (T,B,A,A-1) fp32

    const int n_blocks = in_sizes[0] / (A_DIM * N_DIM);  // T*B = 16384
    attn_kernel<<<dim3(n_blocks), dim3(256), 0, stream>>>(S, Wq, bq, Wk, bk, out);
}